// Round 7
// baseline (93.466 us; speedup 1.0000x reference)
//
#include <hip/hip_runtime.h>

#define DIM 256
#define NPIX 4096
#define BS 16

#define WS_SUMR 0
#define WS_SUME 4096
#define WS_V    8192
#define WS_C    16384

// ---- Kernel 1: spatial row sums via async global->LDS staging.
// 1024 blocks x 4 waves. Each wave owns 2 consecutive rows (16 KB each) of
// one array = 8 chunks of 4 KB. Double-buffered: stage chunk i+1 (4 x
// global_load_lds dwordx4, 1 KB each), s_waitcnt vmcnt(4), reduce chunk i
// from LDS. Guaranteed 8 KB per wave in flight -> 128 KB/CU at 4 blocks/CU.
__global__ __launch_bounds__(256) void k_colsum(const float* __restrict__ rgb,
                                                const float* __restrict__ evt,
                                                float* __restrict__ ws) {
    __shared__ float buf[4][2][1024];   // 32 KB/block
    int t = threadIdx.x, w = t >> 6, l = t & 63;
    int wg = blockIdx.x * 4 + w;        // global wave id, 0..4095
    const float* base;
    int row0, outbase;
    if (wg < 2048) { base = rgb; row0 = wg * 2; outbase = WS_SUMR + row0; }
    else           { base = evt; row0 = (wg - 2048) * 2; outbase = WS_SUME + row0; }
    const float* src = base + (size_t)row0 * NPIX;   // 8192 floats = 8 chunks

    float* lb0 = &buf[w][0][0];
    float* lb1 = &buf[w][1][0];

    // stage chunk c into lb: 4 async 1 KB transfers (lane offset = l*16B auto)
    auto stage = [&](int c, float* lb) {
        const float* g = src + c * 1024 + l * 4;
        #pragma unroll
        for (int k = 0; k < 4; ++k) {
            __builtin_amdgcn_global_load_lds(
                (const __attribute__((address_space(1))) void*)(g + k * 256),
                (__attribute__((address_space(3))) void*)(lb + k * 256),
                16, 0, 0);
        }
    };

    stage(0, lb0);
    float racc = 0.f;
    #pragma unroll
    for (int i = 0; i < 8; ++i) {
        if (i < 7) {
            stage(i + 1, (i & 1) ? lb0 : lb1);
            asm volatile("s_waitcnt vmcnt(4)" ::: "memory");
        } else {
            asm volatile("s_waitcnt vmcnt(0)" ::: "memory");
        }
        const float4* lb = (const float4*)((i & 1) ? lb1 : lb0);
        float4 x0 = lb[l];
        float4 x1 = lb[l + 64];
        float4 x2 = lb[l + 128];
        float4 x3 = lb[l + 192];
        racc += ((x0.x + x0.y) + (x0.z + x0.w)) + ((x1.x + x1.y) + (x1.z + x1.w))
              + ((x2.x + x2.y) + (x2.z + x2.w)) + ((x3.x + x3.y) + (x3.z + x3.w));
        if ((i & 3) == 3) {             // finished a row (4 chunks)
            float s = racc;
            #pragma unroll
            for (int off = 32; off >= 1; off >>= 1)
                s += __shfl_down(s, off, 64);
            if (l == 0) ws[outbase + (i >> 2)] = s;
            racc = 0.f;
        }
    }
}

// ---- Kernel 2: per (b,branch): ksum = Wk.S + N*bk, v = Wq^T.ksum, c = bq.ksum
__global__ __launch_bounds__(256) void k_vvec(
    const float* __restrict__ Wq_a, const float* __restrict__ bq_a,
    const float* __restrict__ Wk_a, const float* __restrict__ bk_a,
    const float* __restrict__ Wq_d, const float* __restrict__ bq_d,
    const float* __restrict__ Wk_d, const float* __restrict__ bk_d,
    float* __restrict__ ws) {
    int b = blockIdx.x, m = blockIdx.y;
    const float* Wq = m ? Wq_d : Wq_a;
    const float* Wk = m ? Wk_d : Wk_a;
    const float* bq = m ? bq_d : bq_a;
    const float* bk = m ? bk_d : bk_a;
    int t = threadIdx.x, w = t >> 6, l = t & 63;
    __shared__ float sS[256], sK[256];
    sS[t] = ws[(m ? WS_SUME : WS_SUMR) + b * 256 + t];
    __syncthreads();
    float4 sv = ((const float4*)sS)[l];
    for (int eo = 0; eo < 64; eo += 4) {
        int e = w * 64 + eo;
        float4 a0 = ((const float4*)(Wk + (size_t)(e + 0) * 256))[l];
        float4 a1 = ((const float4*)(Wk + (size_t)(e + 1) * 256))[l];
        float4 a2 = ((const float4*)(Wk + (size_t)(e + 2) * 256))[l];
        float4 a3 = ((const float4*)(Wk + (size_t)(e + 3) * 256))[l];
        float p0 = a0.x * sv.x + a0.y * sv.y + a0.z * sv.z + a0.w * sv.w;
        float p1 = a1.x * sv.x + a1.y * sv.y + a1.z * sv.z + a1.w * sv.w;
        float p2 = a2.x * sv.x + a2.y * sv.y + a2.z * sv.z + a2.w * sv.w;
        float p3 = a3.x * sv.x + a3.y * sv.y + a3.z * sv.z + a3.w * sv.w;
        #pragma unroll
        for (int off = 32; off >= 1; off >>= 1) {
            p0 += __shfl_down(p0, off, 64);
            p1 += __shfl_down(p1, off, 64);
            p2 += __shfl_down(p2, off, 64);
            p3 += __shfl_down(p3, off, 64);
        }
        if (l == 0) {
            sK[e + 0] = p0 + 4096.0f * bk[e + 0];
            sK[e + 1] = p1 + 4096.0f * bk[e + 1];
            sK[e + 2] = p2 + 4096.0f * bk[e + 2];
            sK[e + 3] = p3 + 4096.0f * bk[e + 3];
        }
    }
    __syncthreads();
    float acc = 0.f;
    #pragma unroll 8
    for (int e = 0; e < 256; ++e)
        acc += Wq[(size_t)e * 256 + t] * sK[e];
    ws[WS_V + (m * BS + b) * 256 + t] = acc;
    float pc = bq[t] * sK[t];
    #pragma unroll
    for (int off = 32; off >= 1; off >>= 1) pc += __shfl_down(pc, off, 64);
    __shared__ float red[4];
    if (l == 0) red[w] = pc;
    __syncthreads();
    if (t == 0)
        ws[WS_C + m * BS + b] = (red[0] + red[1]) + (red[2] + red[3]);
}

// ---- Kernel 3: per-pixel dot / softmax / blend (unchanged from R6).
__global__ __launch_bounds__(256) void k_fuse(
    const float* __restrict__ rgb, const float* __restrict__ evt,
    const float* __restrict__ ws, float* __restrict__ out) {
    int b = blockIdx.y;
    int t = threadIdx.x;
    int wid = t >> 6, lane = t & 63;
    int n = blockIdx.x * 64 + lane;
    int c0 = wid * 64;
    __shared__ float s_va[DIM], s_vd[DIM];
    s_va[t] = ws[WS_V + b * 256 + t];
    s_vd[t] = ws[WS_V + (BS + b) * 256 + t];
    __syncthreads();
    const float* rb = rgb + (size_t)b * DIM * NPIX + n;
    const float* eb = evt + (size_t)b * DIM * NPIX + n;
    float a0 = 0.f, a1 = 0.f, d0 = 0.f, d1 = 0.f;
    #pragma unroll
    for (int cb = 0; cb < 64; cb += 8) {
        float xa[8], xd[8];
        #pragma unroll
        for (int u = 0; u < 8; ++u) xa[u] = rb[(size_t)(c0 + cb + u) * NPIX];
        #pragma unroll
        for (int u = 0; u < 8; ++u) xd[u] = eb[(size_t)(c0 + cb + u) * NPIX];
        asm volatile("" ::: "memory");
        #pragma unroll
        for (int u = 0; u < 8; u += 2) {
            a0 += xa[u]     * s_va[c0 + cb + u];
            a1 += xa[u + 1] * s_va[c0 + cb + u + 1];
            d0 += xd[u]     * s_vd[c0 + cb + u];
            d1 += xd[u + 1] * s_vd[c0 + cb + u + 1];
        }
    }
    float acc_a = a0 + a1, acc_d = d0 + d1;
    __shared__ float s_pa[4][64], s_pd[4][64];
    s_pa[wid][lane] = acc_a; s_pd[wid][lane] = acc_d;
    __syncthreads();
    float va = (s_pa[0][lane] + s_pa[1][lane] + s_pa[2][lane] + s_pa[3][lane]
                + ws[WS_C + b]) * 0.0625f;
    float vd = (s_pd[0][lane] + s_pd[1][lane] + s_pd[2][lane] + s_pd[3][lane]
                + ws[WS_C + BS + b]) * 0.0625f;
    float mm = fmaxf(va, vd);
    float ea = expf(va - mm), ed = expf(vd - mm);
    float inv = 1.0f / (ea + ed);
    float wa = ea * inv, wd = ed * inv;
    float* ob = out + (size_t)b * DIM * NPIX + n;
    #pragma unroll
    for (int cb = 0; cb < 64; cb += 8) {
        float xa[8], xd[8];
        #pragma unroll
        for (int u = 0; u < 8; ++u) xa[u] = rb[(size_t)(c0 + cb + u) * NPIX];
        #pragma unroll
        for (int u = 0; u < 8; ++u) xd[u] = eb[(size_t)(c0 + cb + u) * NPIX];
        asm volatile("" ::: "memory");
        #pragma unroll
        for (int u = 0; u < 8; ++u)
            ob[(size_t)(c0 + cb + u) * NPIX] = wa * xa[u] + wd * xd[u];
    }
}

extern "C" void kernel_launch(void* const* d_in, const int* in_sizes, int n_in,
                              void* d_out, int out_size, void* d_ws, size_t ws_size,
                              hipStream_t stream) {
    const float* rgb  = (const float*)d_in[0];
    const float* evt  = (const float*)d_in[1];
    const float* Wq_a = (const float*)d_in[2];
    const float* bq_a = (const float*)d_in[3];
    const float* Wk_a = (const float*)d_in[4];
    const float* bk_a = (const float*)d_in[5];
    const float* Wq_d = (const float*)d_in[6];
    const float* bq_d = (const float*)d_in[7];
    const float* Wk_d = (const float*)d_in[8];
    const float* bk_d = (const float*)d_in[9];
    float* out = (float*)d_out;
    float* ws  = (float*)d_ws;

    k_colsum<<<1024, 256, 0, stream>>>(rgb, evt, ws);
    dim3 g2(BS, 2);
    k_vvec<<<g2, 256, 0, stream>>>(Wq_a, bq_a, Wk_a, bk_a,
                                   Wq_d, bq_d, Wk_d, bk_d, ws);
    dim3 g3(NPIX / 64, BS);
    k_fuse<<<g3, 256, 0, stream>>>(rgb, evt, ws, out);
}